// Round 15
// baseline (206.111 us; speedup 1.0000x reference)
//
#include <hip/hip_runtime.h>
#include <stdint.h>

typedef unsigned short u16;
typedef unsigned int u32;
typedef __attribute__((ext_vector_type(8))) short short8;
typedef __attribute__((ext_vector_type(4))) float f32x4;

#define L_IN   1323000
#define PAD    1024
#define HOP    441
#define T_FR   3001         // frames per (b,c) row
#define M_ROWS 24008        // 8 * 3001
#define NB     3008         // xb rows per bc (need 3005)
#define RPAD   448          // padded block row length (441 -> 448, 16B-aligned bf16 rows)
#define K1E    2240         // enc K: 5 taps * 448
#define K2     2560         // dec K: 5 taps * 512
#define NT2    40           // dec K-steps (K2/64)
#define W_2PI_N 3.0679615757712823e-3f   // 2*pi/2048

__device__ __forceinline__ u16 f2bf(float f) {
  union { float f; u32 u; } v; v.f = f;
  u32 r = v.u + 0x7FFFu + ((v.u >> 16) & 1u);   // RNE
  return (u16)(r >> 16);
}

__device__ __forceinline__ void gload16(const void* g, void* l) {
  __builtin_amdgcn_global_load_lds(
      (const __attribute__((address_space(1))) u32*)g,
      (__attribute__((address_space(3))) u32*)l, 16, 0, 0);
}

// XCD-aware bijective swizzle for enc: 752 tiles = 8 XCDs x 94; n-fastest within chunk.
__device__ __forceinline__ void tile_from_bid(int bid, int& m0, int& n0) {
  int g = (bid & 7) * 94 + (bid >> 3);
  m0 = (g >> 2) * 128;
  n0 = (g & 3) * 128;
}

// ---------------- prep: blocked bf16 x, folded/rearranged weights ----------------
__global__ void prep_all(const float* __restrict__ x,
                         const float* __restrict__ W_enc, const float* __restrict__ W_dec,
                         u16* __restrict__ xb, u16* __restrict__ wh2,
                         u16* __restrict__ b2, float* __restrict__ zeros) {
  int stride = gridDim.x * blockDim.x;
  int tid0 = blockIdx.x * blockDim.x + threadIdx.x;
  for (int idx = tid0; idx < 64; idx += stride) zeros[idx] = 0.f;
  for (int idx = tid0; idx < 8 * NB * RPAD; idx += stride) {
    int bc = idx / (NB * RPAD);
    int rem = idx - bc * (NB * RPAD);
    int u = rem / RPAD;
    int r = rem - u * RPAD;
    int s = HOP * u + r - PAD;
    int ja = s < 0 ? -s : s;
    int jb = 2 * L_IN - 2 - ja;
    int jr = ja < jb ? ja : jb;          // reflect (no edge repeat)
    xb[idx] = f2bf(x[(size_t)bc * L_IN + jr]);
  }
  for (int idx = tid0; idx < 512 * K1E; idx += stride) {
    int m = idx / K1E;
    int k = idx - m * K1E;
    int j = k / RPAD;
    int r = k - j * RPAD;
    int n = HOP * j + r;
    float v = 0.f;
    if (r < HOP && n < 2048)
      v = (0.5f - 0.5f * cosf(W_2PI_N * (float)n)) * W_enc[m * 2048 + n];
    wh2[idx] = f2bf(v);
  }
  for (int idx = tid0; idx < 512 * K2; idx += stride) {
    int r = idx / K2;
    int k = idx - r * K2;
    int j = k >> 9;
    int m = k & 511;
    int n = HOP * j + r;
    float v = (r < HOP && n < 2048) ? W_dec[n * 512 + m] : 0.f;
    b2[idx] = f2bf(v);
  }
}

// ---------------- enc MFMA core (128x128 tile, 4 waves, 2x2 wavegrid) ----------------
__device__ __forceinline__ void mfma_tile(const u16* sA, const u16* sB, f32x4 acc[4][4],
                                          int lane, int wr, int wc) {
  const int lr = lane & 15;
  const int hi = lane >> 4;
  #pragma unroll
  for (int ks = 0; ks < 2; ++ks) {
    const int off = (((ks * 4 + hi) ^ (lr & 7)) << 3);   // swizzled chunk, u16 elements
    short8 af[4], bg[4];
    #pragma unroll
    for (int f = 0; f < 4; ++f)
      af[f] = *(const short8*)(sA + (wr + f * 16 + lr) * 64 + off);
    #pragma unroll
    for (int f = 0; f < 4; ++f)
      bg[f] = *(const short8*)(sB + (wc + f * 16 + lr) * 64 + off);
    #pragma unroll
    for (int mf = 0; mf < 4; ++mf)
      #pragma unroll
      for (int nf = 0; nf < 4; ++nf)
        acc[mf][nf] = __builtin_amdgcn_mfma_f32_16x16x32_bf16(af[mf], bg[nf], acc[mf][nf], 0, 0, 0);
  }
}

// ---------------- GEMM1: feat[24008,512] = xb-frames @ wh2^T (unchanged R14) ----------------
__global__ __launch_bounds__(256, 2)
void gemm_enc(const u16* __restrict__ xb, const u16* __restrict__ wh2,
              u16* __restrict__ featb) {
  __shared__ u16 sA[128 * 64];
  __shared__ u16 sB[128 * 64];
  const int tid = threadIdx.x;
  const int lane = tid & 63;
  const int w = tid >> 6;
  int m0, n0;
  tile_from_bid(blockIdx.x, m0, n0);
  const int colsw = (((lane & 7) ^ ((lane >> 3) & 7)) << 3);

  const u16* bsrc[4];
  const u16* asrc[4];
  #pragma unroll
  for (int i = 0; i < 4; ++i) {
    int row = (i * 4 + w) * 8 + (lane >> 3);
    bsrc[i] = wh2 + (size_t)(n0 + row) * K1E + colsw;
    int rg = m0 + row;
    int rgc = rg < M_ROWS ? rg : (M_ROWS - 1);
    int bc = rgc / T_FR;
    int t  = rgc - bc * T_FR;
    asrc[i] = xb + ((size_t)bc * NB + t) * RPAD + colsw;
  }

  f32x4 acc[4][4];
  #pragma unroll
  for (int a = 0; a < 4; ++a)
    #pragma unroll
    for (int b = 0; b < 4; ++b) acc[a][b] = f32x4{0.f, 0.f, 0.f, 0.f};

  const int wr = (w >> 1) * 64, wc = (w & 1) * 64;

  for (int kc = 0; kc < K1E; kc += 64) {
    __syncthreads();
    #pragma unroll
    for (int i = 0; i < 4; ++i)
      gload16(bsrc[i] + kc, &sB[(i * 4 + w) * 512]);
    #pragma unroll
    for (int i = 0; i < 4; ++i)
      gload16(asrc[i] + kc, &sA[(i * 4 + w) * 512]);
    __syncthreads();
    mfma_tile(sA, sB, acc, lane, wr, wc);
  }

  #pragma unroll
  for (int mf = 0; mf < 4; ++mf) {
    #pragma unroll
    for (int e = 0; e < 4; ++e) {
      int rg = m0 + wr + mf * 16 + ((lane >> 4) << 2) + e;
      if (rg < M_ROWS) {
        #pragma unroll
        for (int nf = 0; nf < 4; ++nf) {
          int cg = n0 + wc + nf * 16 + (lane & 15);
          featb[(size_t)rg * 512 + cg] = f2bf(acc[mf][nf][e]);
        }
      }
    }
  }
}

// ---------------- dec 8-phase: one MFMA phase (compile-time P, rule #20) ----------------
template<int P>
__device__ __forceinline__ void phase_mfma(const u16* cA, const short8 bfr[4][2],
                                           f32x4 acc[8][4], int wm, int lr, int hi) {
  short8 a0[2], a1[2];
  #pragma unroll
  for (int ks = 0; ks < 2; ++ks) {
    const int ch = ((((ks << 2) | hi) ^ (lr & 7)) << 3);
    a0[ks] = *(const short8*)(cA + wm * 8192 + ((2 * P) * 16 + lr) * 64 + ch);
    a1[ks] = *(const short8*)(cA + wm * 8192 + ((2 * P + 1) * 16 + lr) * 64 + ch);
  }
  __builtin_amdgcn_s_setprio(1);
  #pragma unroll
  for (int ks = 0; ks < 2; ++ks)
    #pragma unroll
    for (int nf = 0; nf < 4; ++nf) {
      acc[2 * P][nf]     = __builtin_amdgcn_mfma_f32_16x16x32_bf16(a0[ks], bfr[nf][ks], acc[2 * P][nf], 0, 0, 0);
      acc[2 * P + 1][nf] = __builtin_amdgcn_mfma_f32_16x16x32_bf16(a1[ks], bfr[nf][ks], acc[2 * P + 1][nf], 0, 0, 0);
    }
  __builtin_amdgcn_s_setprio(0);
}

// ---------------- GEMM2: 256x256 tile, 8 waves, dbuf LDS, counted-vmcnt 4-phase ----------------
__global__ __launch_bounds__(512, 2)
void gemm_dec8(const u16* __restrict__ featb, const u16* __restrict__ b2,
               const u16* __restrict__ zeros, float* __restrict__ out) {
  __shared__ u16 sA[32768];   // [buf][half][128][64] : 64 KB
  __shared__ u16 sB[32768];   // 64 KB
  const int tid = threadIdx.x;
  const int lane = tid & 63;
  const int w = tid >> 6;             // 0..7
  const int wm = w >> 2;              // 0..1 (M)
  const int wn = w & 3;               // 0..3 (N)
  const int lr = lane & 15;
  const int hi = lane >> 4;
  const int n0 = blockIdx.x * 256;    // 0 or 256
  const int m0 = blockIdx.y * 256;
  const int colsw = (((lane & 7) ^ ((lane >> 3) & 7)) << 3);

  // per-thread A sources: (h,l) -> tile row 128h + 8(w+8l) + lane>>3
  int offA[2][2]; int qiv[2][2]; unsigned amask = 0;
  int offB[2][2];
  #pragma unroll
  for (int h = 0; h < 2; ++h)
    #pragma unroll
    for (int l = 0; l < 2; ++l) {
      int rowA = 128 * h + 8 * (w + 8 * l) + (lane >> 3);
      int rg = m0 + rowA;
      int rgc = rg < M_ROWS ? rg : (M_ROWS - 1);
      int bc = rgc / T_FR;
      int qi = rgc - bc * T_FR;
      if (rg < M_ROWS) amask |= 1u << (h * 2 + l);
      qiv[h][l] = qi;
      offA[h][l] = (bc * T_FR + qi + 2) * 512 + colsw;
      int rowB = n0 + 128 * h + 8 * (w + 8 * l) + (lane >> 3);   // < 512
      offB[h][l] = rowB * K2 + colsw;
    }

  f32x4 acc[8][4];
  #pragma unroll
  for (int a = 0; a < 8; ++a)
    #pragma unroll
    for (int b = 0; b < 4; ++b) acc[a][b] = f32x4{0.f, 0.f, 0.f, 0.f};

  // stage helpers: 2 gload16/thread each; dest = wave-uniform base (+lane*16B by HW)
  auto stB = [&](int kc, int bufi, int h) {
    gload16(b2 + offB[h][0] + kc, sB + bufi * 16384 + h * 8192 + w * 512);
    gload16(b2 + offB[h][1] + kc, sB + bufi * 16384 + h * 8192 + (w + 8) * 512);
  };
  auto stA = [&](int kc, int bufi, int l) {
    int jt = kc >> 9;                  // tap 0..4 (BK=64 never straddles a tap)
    #pragma unroll
    for (int h = 0; h < 2; ++h) {
      int tt = qiv[h][l] + 2 - jt;
      bool ok = ((amask >> (h * 2 + l)) & 1) && tt >= 0 && tt <= 3000;
      const u16* pa = ok ? (featb + offA[h][l] + kc - 1024 * jt) : (zeros + colsw);
      gload16(pa, sA + bufi * 16384 + h * 8192 + (w + 8 * l) * 512);
    }
  };

  // prologue: stage tile 0 into buf 0 (stream order: B-h0, B-h1, A-low, A-high)
  stB(0, 0, 0); stB(0, 0, 1); stA(0, 0, 0); stA(0, 0, 1);

  #pragma unroll 1
  for (int t = 0; t < NT2; ++t) {
    const int buf = t & 1, nxt = buf ^ 1;
    const int kcn = (t + 1) * 64;
    const u16* cA = sA + buf * 16384;
    const u16* cB = sB + buf * 16384;
    // ---- phase 0: stage B-h0(t+1); wait B(all)+A-low of tile t; MFMA mf0,1 ----
    if (t < NT2 - 1) {
      stB(kcn, nxt, 0);
      asm volatile("s_waitcnt vmcnt(4)\n\ts_barrier" ::: "memory");
    } else {
      asm volatile("s_waitcnt vmcnt(2)\n\ts_barrier" ::: "memory");
    }
    short8 bfr[4][2];
    #pragma unroll
    for (int nf = 0; nf < 4; ++nf)
      #pragma unroll
      for (int ks = 0; ks < 2; ++ks) {
        int rb = (wn & 1) * 64 + nf * 16 + lr;
        bfr[nf][ks] = *(const short8*)(cB + (wn >> 1) * 8192 + rb * 64 +
                                       ((((ks << 2) | hi) ^ (lr & 7)) << 3));
      }
    phase_mfma<0>(cA, bfr, acc, wm, lr, hi);
    asm volatile("s_barrier" ::: "memory");
    // ---- phase 1: stage B-h1(t+1); MFMA mf2,3 ----
    if (t < NT2 - 1) stB(kcn, nxt, 1);
    asm volatile("s_barrier" ::: "memory");
    phase_mfma<1>(cA, bfr, acc, wm, lr, hi);
    asm volatile("s_barrier" ::: "memory");
    // ---- phase 2: stage A-low(t+1); wait A-high of tile t; MFMA mf4,5 ----
    if (t < NT2 - 1) {
      stA(kcn, nxt, 0);
      asm volatile("s_waitcnt vmcnt(6)\n\ts_barrier" ::: "memory");
    } else {
      asm volatile("s_waitcnt vmcnt(0)\n\ts_barrier" ::: "memory");
    }
    phase_mfma<2>(cA, bfr, acc, wm, lr, hi);
    asm volatile("s_barrier" ::: "memory");
    // ---- phase 3: stage A-high(t+1); MFMA mf6,7 ----
    if (t < NT2 - 1) stA(kcn, nxt, 1);
    asm volatile("s_barrier" ::: "memory");
    phase_mfma<3>(cA, bfr, acc, wm, lr, hi);
    asm volatile("s_barrier" ::: "memory");
  }

  // epilogue: (bc,qi,r) -> out i = 441*qi + r - 142, scaled by 1/win_norm.
  float hh[4][5];
  float rnfull[4];
  int cgv[4];
  #pragma unroll
  for (int nf = 0; nf < 4; ++nf) {
    int cg = n0 + wn * 64 + nf * 16 + lr;
    cgv[nf] = cg;
    float s = 0.f;
    #pragma unroll
    for (int j = 0; j < 5; ++j) {
      int n = HOP * j + cg;
      float h = (cg < HOP && n < 2048) ? (0.5f - 0.5f * cosf(W_2PI_N * (float)n)) : 0.f;
      hh[nf][j] = h;
      s += h;
    }
    rnfull[nf] = 1.f / fmaxf(s, 1e-8f);
  }

  #pragma unroll
  for (int mf = 0; mf < 8; ++mf) {
    #pragma unroll
    for (int e = 0; e < 4; ++e) {
      int rg = m0 + wm * 128 + mf * 16 + (hi << 2) + e;
      if (rg < M_ROWS) {
        int bc = rg / T_FR;
        int qi = rg - bc * T_FR;
        int ib = HOP * qi - 142;
        bool interior = (qi >= 2) && (qi <= 2998);
        #pragma unroll
        for (int nf = 0; nf < 4; ++nf) {
          if (cgv[nf] < HOP) {
            int oi = ib + cgv[nf];
            if (oi >= 0 && oi < L_IN) {
              float rn;
              if (interior) {
                rn = rnfull[nf];
              } else {
                float s = 0.f;
                #pragma unroll
                for (int j = 0; j < 5; ++j)
                  if ((unsigned)(qi + 2 - j) <= 3000u) s += hh[nf][j];
                rn = 1.f / fmaxf(s, 1e-8f);
              }
              out[(size_t)bc * L_IN + oi] = acc[mf][nf][e] * rn;
            }
          }
        }
      }
    }
  }
}

// ---------------- launch ----------------

extern "C" void kernel_launch(void* const* d_in, const int* in_sizes, int n_in,
                              void* d_out, int out_size, void* d_ws, size_t ws_size,
                              hipStream_t stream) {
  const float* x     = (const float*)d_in[0];
  const float* W_enc = (const float*)d_in[1];
  const float* W_dec = (const float*)d_in[2];
  float* out = (float*)d_out;
  char* ws = (char*)d_ws;

  // xb lives in d_out (21,561,344 B < 42,336,000 B): written by prep, read by enc,
  // then gemm_dec8's epilogue bijectively overwrites every d_out element last.
  u16* xb = (u16*)d_out;

  // workspace layout (total 29,499,648 B ~= 28.1 MiB)
  u16*   wh2   = (u16*)  (ws + 0);            // 512*2240*2  =  2,293,760
  u16*   b2    = (u16*)  (ws + 2293760);      // 512*2560*2  =  2,621,440
  u16*   featb = (u16*)  (ws + 4915200);      // 24008*512*2 = 24,584,192
  float* zeros = (float*)(ws + 29499392);     // 256 B zero block (gather redirect)

  prep_all<<<2048, 256, 0, stream>>>(x, W_enc, W_dec, xb, wh2, b2, zeros);
  gemm_enc<<<752, 256, 0, stream>>>(xb, wh2, featb);
  gemm_dec8<<<dim3(2, 94), 512, 0, stream>>>(featb, b2, (const u16*)zeros, out);
}